// Round 1
// baseline (2099.736 us; speedup 1.0000x reference)
//
#include <hip/hip_runtime.h>
#include <hip/hip_bf16.h>

// Shapes: B=8 C=512 T=32 H=W=7 P=49 N=8 E=64 K_WIN=7 L=343
// x: (B,C,T,H,W) fp32; out: same, fp32.

static __device__ __forceinline__ float bf2f(unsigned short u){
  union { unsigned int i; float f; } x; x.i = ((unsigned int)u) << 16; return x.f;
}
static __device__ __forceinline__ unsigned short f2bf(float f){
  union { __hip_bfloat16 h; unsigned short u; } x; x.h = __float2bfloat16(f); return x.u;
}

// ---------------- Kernel A: per-channel mean/var -> scale/shift ----------------
__global__ __launch_bounds__(256) void stats_kernel(const float* __restrict__ x,
    const float* __restrict__ gamma, const float* __restrict__ beta,
    float* __restrict__ scale, float* __restrict__ shift){
  const int c = blockIdx.x;
  const int tid = threadIdx.x;
  float s1 = 0.f, s2 = 0.f;
  for (int i = tid; i < 8*1568; i += 256){
    int b = i / 1568, r = i - b*1568;
    float v = x[(size_t)b*802816 + (size_t)c*1568 + r];
    s1 += v; s2 += v*v;
  }
  #pragma unroll
  for (int off = 32; off > 0; off >>= 1){
    s1 += __shfl_down(s1, off);
    s2 += __shfl_down(s2, off);
  }
  __shared__ float r1[4], r2[4];
  int wave = tid >> 6, lane = tid & 63;
  if (lane == 0){ r1[wave] = s1; r2[wave] = s2; }
  __syncthreads();
  if (tid == 0){
    float t1 = r1[0]+r1[1]+r1[2]+r1[3];
    float t2 = r2[0]+r2[1]+r2[2]+r2[3];
    const float inv = 1.f/12544.f;
    float mean = t1*inv;
    float var  = t2*inv - mean*mean;
    float sc = gamma[c]*rsqrtf(var + 1e-5f);
    scale[c] = sc;
    shift[c] = beta[c] - mean*sc;
  }
}

// ---------------- Kernel C: QKV projections ----------------
// block = (b,t); 512 threads (8 waves). Stage normalized X (512x49) in LDS fp32.
// Rows r in [0,1536): which=r/512 (q,k,v), n=(r%512)/64, e=r%64.
// Wave-uniform row groups -> W via scalar loads.
__global__ __launch_bounds__(512) void qkv_kernel(const float* __restrict__ x,
    const float* __restrict__ scale, const float* __restrict__ shift,
    const float* __restrict__ Wq, const float* __restrict__ bq,
    const float* __restrict__ Wk, const float* __restrict__ bk,
    const float* __restrict__ Wv, const float* __restrict__ bv,
    unsigned short* __restrict__ Qw, unsigned short* __restrict__ Kw,
    unsigned short* __restrict__ Vw){
  __shared__ float Xs[512][50];
  const int bt = blockIdx.x;
  const int b = bt >> 5, t = bt & 31;
  const size_t xbase = (size_t)b*802816 + (size_t)t*49;
  for (int i = threadIdx.x; i < 512*49; i += 512){
    int c = i / 49, p = i - c*49;
    Xs[c][p] = x[xbase + (size_t)c*1568 + p]*scale[c] + shift[c];
  }
  __syncthreads();
  const int wave = __builtin_amdgcn_readfirstlane(threadIdx.x >> 6);
  const int lane = threadIdx.x & 63;
  const int p = lane < 49 ? lane : 48;
  for (int j = 0; j < 24; ++j){
    const int g  = wave + 8*j;      // 0..191
    const int r0 = g*8;
    const int which = r0 >> 9;
    const int n  = (r0 >> 6) & 7;
    const int e0 = r0 & 63;
    const float* W    = which == 0 ? Wq : (which == 1 ? Wk : Wv);
    const float* bias = which == 0 ? bq : (which == 1 ? bk : bv);
    unsigned short* Out = which == 0 ? Qw : (which == 1 ? Kw : Vw);
    const float* Wr = W + ((size_t)n*64 + e0)*512;
    float acc[8];
    #pragma unroll
    for (int i = 0; i < 8; ++i) acc[i] = bias[n*64 + e0 + i];
    #pragma unroll 4
    for (int c = 0; c < 512; ++c){
      const float xv = Xs[c][p];
      #pragma unroll
      for (int i = 0; i < 8; ++i) acc[i] = fmaf(Wr[i*512 + c], xv, acc[i]);
    }
    if (lane < 49){
      const size_t obase = ((((size_t)b*8 + n)*32 + t)*64 + e0)*49 + p;
      #pragma unroll
      for (int i = 0; i < 8; ++i) Out[obase + (size_t)i*49] = f2bf(acc[i]);
    }
  }
}

// ---------------- Kernel D: local attention ----------------
// block = (b,n,t). S (49 x 7*49) via per-slice 49x49 blocks; pad slices analytic
// (k=bk, v=bv). Online: full S in LDS (bf16), two-pass softmax, then Y.
__global__ __launch_bounds__(256) void attn_kernel(
    const unsigned short* __restrict__ Qw, const unsigned short* __restrict__ Kw,
    const unsigned short* __restrict__ Vw,
    const float* __restrict__ bk, const float* __restrict__ bv,
    unsigned short* __restrict__ Yw){
  __shared__ float Qs[64][52];
  __shared__ float KVs[64][52];
  __shared__ unsigned short Ss[52][364];  // [p][s*52 + l], pad cols/rows zero
  __shared__ float bkS[64], bvS[64];
  __shared__ float padl[64], mS[64], invd[64], padwS[64];
  __shared__ float pm[49][5], ps[49][5];
  const int tid = threadIdx.x;
  const int blk = blockIdx.x;
  const int t = blk & 31, n = (blk >> 5) & 7, b = blk >> 8;
  const size_t base_bn = ((size_t)b*8 + n)*32;
  const size_t qbase = (base_bn + t)*3136;
  for (int i = tid; i < 64*52; i += 256){
    int e = i / 52, p = i - e*52;
    Qs[e][p] = (p < 49) ? bf2f(Qw[qbase + e*49 + p]) : 0.f;
  }
  if (tid < 64){ bkS[tid] = bk[n*64 + tid]; bvS[tid] = bv[n*64 + tid]; }
  for (int i = tid; i < 52*364; i += 256) (&Ss[0][0])[i] = 0;
  __syncthreads();
  if (tid < 49){
    float s = 0.f;
    #pragma unroll 8
    for (int e = 0; e < 64; ++e) s += Qs[e][tid]*bkS[e];
    padl[tid] = s;
  }
  const int slo = (3 - t) > 0 ? (3 - t) : 0;
  const int shi = (34 - t) < 6 ? (34 - t) : 6;
  const int n_pad = 7 - (shi - slo + 1);
  const int tp = tid % 13, tl = tid / 13;
  const int p0 = tp*4, l0g = tl*4;
  // ---- S = Q^T K per in-range slice ----
  for (int s = slo; s <= shi; ++s){
    const int tt = t + s - 3;
    __syncthreads();
    const size_t kb = (base_bn + tt)*3136;
    for (int i = tid; i < 64*52; i += 256){
      int e = i / 52, p = i - e*52;
      KVs[e][p] = (p < 49) ? bf2f(Kw[kb + e*49 + p]) : 0.f;
    }
    __syncthreads();
    if (tid < 169){
      float acc[4][4] = {};
      for (int e = 0; e < 64; ++e){
        float4 q4 = *(const float4*)&Qs[e][p0];
        float4 k4 = *(const float4*)&KVs[e][l0g];
        float qa[4] = {q4.x, q4.y, q4.z, q4.w};
        float ka[4] = {k4.x, k4.y, k4.z, k4.w};
        #pragma unroll
        for (int i = 0; i < 4; ++i)
          #pragma unroll
          for (int jj = 0; jj < 4; ++jj)
            acc[i][jj] = fmaf(qa[i], ka[jj], acc[i][jj]);
      }
      #pragma unroll
      for (int i = 0; i < 4; ++i){
        if (p0 + i < 49){
          #pragma unroll
          for (int jj = 0; jj < 4; ++jj)
            if (l0g + jj < 49) Ss[p0 + i][s*52 + l0g + jj] = f2bf(acc[i][jj]);
        }
      }
    }
  }
  __syncthreads();
  // ---- softmax (pad handled analytically) ----
  const int sp = tid / 5, sj = tid - (tid/5)*5;
  const int cbg = sj*73, ceg = (cbg + 73) < 364 ? (cbg + 73) : 364;
  if (tid < 245){
    float mx = -1e30f;
    for (int col = cbg; col < ceg; ++col){
      int s = col / 52, l = col - s*52;
      if (s < slo || s > shi || l >= 49) continue;
      mx = fmaxf(mx, bf2f(Ss[sp][col]));
    }
    pm[sp][sj] = mx;
  }
  __syncthreads();
  if (tid < 49){
    float m = fmaxf(fmaxf(fmaxf(pm[tid][0], pm[tid][1]), fmaxf(pm[tid][2], pm[tid][3])), pm[tid][4]);
    if (n_pad > 0) m = fmaxf(m, padl[tid]);
    mS[tid] = m;
  }
  __syncthreads();
  if (tid < 245){
    const float m = mS[sp];
    float sum = 0.f;
    for (int col = cbg; col < ceg; ++col){
      int s = col / 52, l = col - s*52;
      if (s < slo || s > shi || l >= 49) continue;
      float a = __expf(bf2f(Ss[sp][col]) - m);
      Ss[sp][col] = f2bf(a);
      sum += a;
    }
    ps[sp][sj] = sum;
  }
  __syncthreads();
  if (tid < 49){
    float sum = ps[tid][0]+ps[tid][1]+ps[tid][2]+ps[tid][3]+ps[tid][4];
    float pw = (n_pad > 0) ? (float)n_pad*49.f*__expf(padl[tid] - mS[tid]) : 0.f;
    float inv = 1.f/(sum + pw);
    invd[tid]  = inv;
    padwS[tid] = pw*inv;
  }
  // ---- Y = alpha @ V (+ pad rank-1 term) ----
  const int te = tid & 15, tq = tid >> 4;
  const int e0 = te*4, pp0 = tq*4;
  float acc2[4][4] = {};
  for (int s = slo; s <= shi; ++s){
    const int tt = t + s - 3;
    __syncthreads();
    const size_t vb = (base_bn + tt)*3136;
    for (int i = tid; i < 64*52; i += 256){
      int e = i / 52, p = i - e*52;
      KVs[e][p] = (p < 49) ? bf2f(Vw[vb + e*49 + p]) : 0.f;
    }
    __syncthreads();
    if (tid < 208){
      for (int lt = 0; lt < 13; ++lt){
        const int l0 = lt*4;
        float av[4][4];
        #pragma unroll
        for (int pi = 0; pi < 4; ++pi){
          ushort4 u = *(const ushort4*)&Ss[pp0 + pi][s*52 + l0];
          av[pi][0] = bf2f(u.x); av[pi][1] = bf2f(u.y);
          av[pi][2] = bf2f(u.z); av[pi][3] = bf2f(u.w);
        }
        #pragma unroll
        for (int ei = 0; ei < 4; ++ei){
          float4 v4 = *(const float4*)&KVs[e0 + ei][l0];
          float va[4] = {v4.x, v4.y, v4.z, v4.w};
          #pragma unroll
          for (int pi = 0; pi < 4; ++pi)
            #pragma unroll
            for (int li = 0; li < 4; ++li)
              acc2[ei][pi] = fmaf(av[pi][li], va[li], acc2[ei][pi]);
        }
      }
    }
  }
  if (tid < 208){
    #pragma unroll
    for (int pi = 0; pi < 4; ++pi){
      const int p = pp0 + pi;
      if (p < 49){
        const float inv = invd[p], pw = padwS[p];
        #pragma unroll
        for (int ei = 0; ei < 4; ++ei){
          float val = acc2[ei][pi]*inv + pw*bvS[e0 + ei];
          Yw[qbase + (size_t)(e0 + ei)*49 + p] = f2bf(val);
        }
      }
    }
  }
}

// ---------------- Kernel E: output projection + head-mean + residual ----------------
// z[c,p] = ( sum_{n,e} Wo[n,c,e] Y[n,e,p] + sum_n bo[n,c] ) / 8 ; out = z + xb
__global__ __launch_bounds__(512) void out_kernel(
    const unsigned short* __restrict__ Yw,
    const float* __restrict__ Wo, const float* __restrict__ bo,
    const float* __restrict__ x, const float* __restrict__ scale,
    const float* __restrict__ shift, float* __restrict__ out){
  __shared__ float Ys[512][50];
  const int bt = blockIdx.x;
  const int b = bt >> 5, t = bt & 31;
  for (int i = threadIdx.x; i < 512*49; i += 512){
    int ne = i / 49, p = i - ne*49;
    Ys[ne][p] = bf2f(Yw[((((size_t)b*8 + (ne >> 6))*32 + t)*64 + (ne & 63))*49 + p]);
  }
  __syncthreads();
  const int wave = __builtin_amdgcn_readfirstlane(threadIdx.x >> 6);
  const int lane = threadIdx.x & 63;
  const int p = lane < 49 ? lane : 48;
  for (int j = 0; j < 8; ++j){
    const int g  = wave + 8*j;   // 0..63
    const int c0 = g*8;
    float acc[8];
    #pragma unroll
    for (int i = 0; i < 8; ++i){
      float s = 0.f;
      #pragma unroll
      for (int nn = 0; nn < 8; ++nn) s += bo[nn*512 + c0 + i];
      acc[i] = s;
    }
    #pragma unroll 2
    for (int ne = 0; ne < 512; ++ne){
      const float yv = Ys[ne][p];
      const int nn = ne >> 6, e = ne & 63;
      #pragma unroll
      for (int i = 0; i < 8; ++i)
        acc[i] = fmaf(Wo[((size_t)nn*512 + c0 + i)*64 + e], yv, acc[i]);
    }
    if (lane < 49){
      #pragma unroll
      for (int i = 0; i < 8; ++i){
        const int c = c0 + i;
        const size_t xi = ((size_t)b*512 + c)*1568 + (size_t)t*49 + p;
        out[xi] = acc[i]*0.125f + x[xi]*scale[c] + shift[c];
      }
    }
  }
}

extern "C" void kernel_launch(void* const* d_in, const int* in_sizes, int n_in_,
                              void* d_out, int out_size, void* d_ws, size_t ws_size,
                              hipStream_t stream){
  const float* x     = (const float*)d_in[0];
  const float* gamma = (const float*)d_in[1];
  const float* beta  = (const float*)d_in[2];
  const float* Wq    = (const float*)d_in[3];
  const float* bq    = (const float*)d_in[4];
  const float* Wk    = (const float*)d_in[5];
  const float* bk    = (const float*)d_in[6];
  const float* Wv    = (const float*)d_in[7];
  const float* bv    = (const float*)d_in[8];
  const float* Wo    = (const float*)d_in[9];
  const float* bo    = (const float*)d_in[10];
  float* out = (float*)d_out;

  char* ws = (char*)d_ws;
  float* scale = (float*)ws;
  float* shift = scale + 512;
  const size_t AE = 6422528;  // B*N*T*E*P
  unsigned short* Qw = (unsigned short*)(ws + 4096);
  unsigned short* Kw = Qw + AE;
  unsigned short* Vw = Kw + AE;
  unsigned short* Yw = Vw + AE;

  hipLaunchKernelGGL(stats_kernel, dim3(512), dim3(256), 0, stream,
                     x, gamma, beta, scale, shift);
  hipLaunchKernelGGL(qkv_kernel, dim3(256), dim3(512), 0, stream,
                     x, scale, shift, Wq, bq, Wk, bk, Wv, bv, Qw, Kw, Vw);
  hipLaunchKernelGGL(attn_kernel, dim3(2048), dim3(256), 0, stream,
                     Qw, Kw, Vw, bk, bv, Yw);
  hipLaunchKernelGGL(out_kernel, dim3(256), dim3(512), 0, stream,
                     Yw, Wo, bo, x, scale, shift, out);
}

// Round 2
// 203.281 us; speedup vs baseline: 10.3292x; 10.3292x over previous
//
#include <hip/hip_runtime.h>
#include <hip/hip_bf16.h>

// Shapes: B=8 C=512 T=32 H=W=7 P=49 N=8 E=64 K_WIN=7
// x: (B,C,T,H,W) fp32; out same fp32.

typedef float f32x4 __attribute__((ext_vector_type(4)));
typedef short s16x8 __attribute__((ext_vector_type(8)));
typedef short s16x4 __attribute__((ext_vector_type(4)));
typedef __bf16 bf16x8 __attribute__((ext_vector_type(8)));

static __device__ __forceinline__ float bf2f(unsigned short u){
  union { unsigned int i; float f; } x; x.i = ((unsigned int)u) << 16; return x.f;
}
static __device__ __forceinline__ unsigned short f2bf(float f){
  union { __hip_bfloat16 h; unsigned short u; } x; x.h = __float2bfloat16(f); return x.u;
}
static __device__ __forceinline__ f32x4 mfma16(s16x8 a, s16x8 b, f32x4 c){
  return __builtin_amdgcn_mfma_f32_16x16x32_bf16(
      __builtin_bit_cast(bf16x8, a), __builtin_bit_cast(bf16x8, b), c, 0, 0, 0);
}

// ---------------- per-channel stats -> scale/shift ----------------
__global__ __launch_bounds__(256) void stats_kernel(const float* __restrict__ x,
    const float* __restrict__ gamma, const float* __restrict__ beta,
    float* __restrict__ scale, float* __restrict__ shift){
  const int c = blockIdx.x, tid = threadIdx.x;
  float s1 = 0.f, s2 = 0.f;
  const float* xc = x + (size_t)c*1568;
  for (int i = tid; i < 3136; i += 256){
    int b = i / 392, j = i - b*392;
    f32x4 v = *(const f32x4*)(xc + (size_t)b*802816 + j*4);
    s1 += v[0]+v[1]+v[2]+v[3];
    s2 += v[0]*v[0]+v[1]*v[1]+v[2]*v[2]+v[3]*v[3];
  }
  #pragma unroll
  for (int off = 32; off > 0; off >>= 1){
    s1 += __shfl_down(s1, off);
    s2 += __shfl_down(s2, off);
  }
  __shared__ float r1[4], r2[4];
  int wave = tid >> 6, lane = tid & 63;
  if (lane == 0){ r1[wave] = s1; r2[wave] = s2; }
  __syncthreads();
  if (tid == 0){
    float t1 = r1[0]+r1[1]+r1[2]+r1[3];
    float t2 = r2[0]+r2[1]+r2[2]+r2[3];
    const float inv = 1.f/12544.f;
    float mean = t1*inv;
    float var  = t2*inv - mean*mean;
    float sc = gamma[c]*rsqrtf(var + 1e-5f);
    scale[c] = sc;
    shift[c] = beta[c] - mean*sc;
  }
}

// ---------------- pack weights to bf16 ----------------
__global__ __launch_bounds__(512) void pack_kernel(const float* __restrict__ Wq,
    const float* __restrict__ Wk, const float* __restrict__ Wv,
    const float* __restrict__ Wo, const float* __restrict__ bo,
    unsigned short* __restrict__ Wall, unsigned short* __restrict__ Wo2,
    float* __restrict__ bo_sum){
  int i = blockIdx.x*512 + threadIdx.x;
  if (i < 786432){
    const float* W = (i < 262144) ? Wq : (i < 524288 ? Wk : Wv);
    Wall[i] = f2bf(W[i & 262143]);
  } else if (i < 1048576){
    int j = i - 786432;
    int c = j >> 9, k = j & 511, nn = k >> 6, e = k & 63;
    Wo2[j] = f2bf(Wo[((size_t)nn*512 + c)*64 + e] * 0.125f);
  } else if (i < 1049088){
    int c = i - 1048576;
    float s = 0.f;
    #pragma unroll
    for (int nn = 0; nn < 8; ++nn) s += bo[nn*512 + c];
    bo_sum[c] = s * 0.125f;
  }
}

// ---------------- normalize + transpose x -> Xt[bt][p(64)][c(512)] bf16 ----------------
__global__ __launch_bounds__(256) void xt_kernel(const float* __restrict__ x,
    const float* __restrict__ scale, const float* __restrict__ shift,
    unsigned short* __restrict__ Xt){
  __shared__ unsigned short Xc[512][52];
  const int bt = blockIdx.x, b = bt >> 5, t = bt & 31, tid = threadIdx.x;
  const float* xb = x + (size_t)b*802816 + t*49;
  for (int i = tid; i < 512*49; i += 256){
    int c = i / 49, p = i - c*49;
    Xc[c][p] = f2bf(xb[(size_t)c*1568 + p]*scale[c] + shift[c]);
  }
  __syncthreads();
  unsigned short* dst = Xt + (size_t)bt*32768;
  for (int i = tid; i < 4096; i += 256){
    int p = i & 63, c0 = (i >> 6) << 3;
    s16x8 v;
    #pragma unroll
    for (int j = 0; j < 8; ++j) v[j] = (p < 49) ? (short)Xc[c0+j][p] : (short)0;
    *(s16x8*)(dst + p*512 + c0) = v;
  }
}

// ---------------- QKV projections (MFMA) ----------------
// block=(b,t), 8 waves; wave handles 192 rows of Wall (1536x512) x Xt(512x64).
// Q rows get *log2e (softmax via exp2). Writes Qg/Kg p-major [p][64], Vg e-major [64][52].
__global__ __launch_bounds__(512,2) void qkv_kernel(const unsigned short* __restrict__ Wall,
    const unsigned short* __restrict__ Xt,
    const float* __restrict__ bq, const float* __restrict__ bk, const float* __restrict__ bv,
    unsigned short* __restrict__ Qg, unsigned short* __restrict__ Kg,
    unsigned short* __restrict__ Vg){
  __shared__ float Blds[1536];
  const int bt = blockIdx.x, b = bt >> 5, t = bt & 31, tid = threadIdx.x;
  for (int i = tid; i < 1536; i += 512)
    Blds[i] = (i < 512) ? bq[i] : (i < 1024 ? bk[i-512] : bv[i-1024]);
  __syncthreads();
  const int wave = __builtin_amdgcn_readfirstlane(tid >> 6);
  const int lane = tid & 63, g = lane >> 4, l15 = lane & 15, g4 = (lane >> 4)*4;
  const unsigned short* XtB = Xt + (size_t)bt*32768;
  f32x4 acc[12][4];
  #pragma unroll
  for (int mi = 0; mi < 12; ++mi)
    #pragma unroll
    for (int ni = 0; ni < 4; ++ni) acc[mi][ni] = 0.f;
  const int rowb0 = wave*192;
  #pragma unroll 2
  for (int ks = 0; ks < 16; ++ks){
    s16x8 Bf[4];
    #pragma unroll
    for (int ni = 0; ni < 4; ++ni)
      Bf[ni] = *(const s16x8*)(XtB + (ni*16 + l15)*512 + ks*32 + g*8);
    #pragma unroll
    for (int mi = 0; mi < 12; ++mi){
      s16x8 Af = *(const s16x8*)(Wall + (size_t)(rowb0 + mi*16 + l15)*512 + ks*32 + g*8);
      #pragma unroll
      for (int ni = 0; ni < 4; ++ni)
        acc[mi][ni] = mfma16(Af, Bf[ni], acc[mi][ni]);
    }
  }
  #pragma unroll
  for (int mi = 0; mi < 12; ++mi){
    const int rowbase = rowb0 + mi*16;
    const int which = rowbase >> 9, nh = (rowbase >> 6) & 7, eb = (rowbase & 63) + g4;
    const f32x4 bias = *(const f32x4*)&Blds[rowbase + g4];
    const size_t bnt = ((size_t)(b*8 + nh)*32 + t);
    #pragma unroll
    for (int ni = 0; ni < 4; ++ni){
      const int p = ni*16 + l15;
      f32x4 v = acc[mi][ni] + bias;
      if (which == 0) v *= 1.4426950408889634f;
      if (p < 49){
        if (which < 2){
          unsigned short* dstp = (which == 0 ? Qg : Kg) + (bnt*49 + p)*64 + eb;
          s16x4 u;
          #pragma unroll
          for (int r = 0; r < 4; ++r) u[r] = (short)f2bf(v[r]);
          *(s16x4*)dstp = u;
        } else {
          unsigned short* vb = Vg + bnt*3328 + p;
          #pragma unroll
          for (int r = 0; r < 4; ++r) vb[(size_t)(eb + r)*52] = f2bf(v[r]);
        }
      }
    }
  }
}

// ---------------- local attention (MFMA, online softmax in registers) ----------------
// block=(b,t) (XCD-swizzled), wave = head. S^T = K^T Q so softmax axis is in regs;
// P feeds PV directly (k-order matched to D layout). Pad slices analytic.
__global__ __launch_bounds__(512,2) void attn_kernel(const unsigned short* __restrict__ Qg,
    const unsigned short* __restrict__ Kg, const unsigned short* __restrict__ Vg,
    const float* __restrict__ bk, const float* __restrict__ bv,
    unsigned short* __restrict__ Yg){
  const int bid = blockIdx.x;
  const int bt = ((bid & 7) << 5) | (bid >> 3);
  const int b = bt >> 5, t = bt & 31, tid = threadIdx.x;
  const int n = __builtin_amdgcn_readfirstlane(tid >> 6);
  const int lane = tid & 63, g = lane >> 4, l15 = lane & 15, g4 = (lane >> 4)*4;
  const size_t bnt = ((size_t)(b*8 + n)*32 + t);
  const unsigned short* Qb = Qg + bnt*3136;
  s16x8 Qf[4][2];
  #pragma unroll
  for (int ni = 0; ni < 4; ++ni)
    #pragma unroll
    for (int ks = 0; ks < 2; ++ks)
      Qf[ni][ks] = *(const s16x8*)(Qb + (ni*16 + l15)*64 + ks*32 + g*8);
  // pad logit (k = bk) per p-column
  const float* bkp = bk + n*64;
  f32x4 bkf[2][2];
  bkf[0][0] = *(const f32x4*)(bkp + g*8);      bkf[0][1] = *(const f32x4*)(bkp + g*8 + 4);
  bkf[1][0] = *(const f32x4*)(bkp + 32 + g*8); bkf[1][1] = *(const f32x4*)(bkp + 32 + g*8 + 4);
  float pad_l[4];
  #pragma unroll
  for (int ni = 0; ni < 4; ++ni){
    float s = 0.f;
    #pragma unroll
    for (int ks = 0; ks < 2; ++ks)
      #pragma unroll
      for (int h = 0; h < 2; ++h)
        #pragma unroll
        for (int j = 0; j < 4; ++j)
          s += bf2f((unsigned short)Qf[ni][ks][h*4+j]) * bkf[ks][h][j];
    s += __shfl_xor(s, 16); s += __shfl_xor(s, 32);
    pad_l[ni] = s;
  }
  float m_run[4], d_run[4];
  f32x4 Yacc[4][4];
  #pragma unroll
  for (int ni = 0; ni < 4; ++ni){
    m_run[ni] = -1e30f; d_run[ni] = 0.f;
    #pragma unroll
    for (int me = 0; me < 4; ++me) Yacc[me][ni] = 0.f;
  }
  int slo = 3 - t; if (slo < 0) slo = 0;
  int shi = 34 - t; if (shi > 6) shi = 6;
  for (int s = slo; s <= shi; ++s){
    const int tt = t + s - 3;
    const unsigned short* Kb = Kg + ((size_t)(b*8 + n)*32 + tt)*3136;
    const unsigned short* Vb = Vg + ((size_t)(b*8 + n)*32 + tt)*3328;
    f32x4 S[4][4];
    #pragma unroll
    for (int mi = 0; mi < 4; ++mi)
      #pragma unroll
      for (int ni = 0; ni < 4; ++ni) S[mi][ni] = 0.f;
    #pragma unroll
    for (int ks = 0; ks < 2; ++ks)
      #pragma unroll
      for (int mi = 0; mi < 4; ++mi){
        s16x8 Kf = *(const s16x8*)(Kb + (mi*16 + l15)*64 + ks*32 + g*8);
        #pragma unroll
        for (int ni = 0; ni < 4; ++ni)
          S[mi][ni] = mfma16(Kf, Qf[ni][ks], S[mi][ni]);
      }
    // mask l >= 49 (only mi==3 tiles: l = 48 + g4 + r)
    #pragma unroll
    for (int r = 0; r < 4; ++r){
      const bool bad = (g4 + r) >= 1;
      #pragma unroll
      for (int ni = 0; ni < 4; ++ni)
        S[3][ni][r] = bad ? -1e30f : S[3][ni][r];
    }
    // online softmax per p-column (base-2; Q pre-scaled by log2e)
    #pragma unroll
    for (int ni = 0; ni < 4; ++ni){
      float mx = -1e30f;
      #pragma unroll
      for (int mi = 0; mi < 4; ++mi)
        #pragma unroll
        for (int r = 0; r < 4; ++r) mx = fmaxf(mx, S[mi][ni][r]);
      mx = fmaxf(mx, __shfl_xor(mx, 16));
      mx = fmaxf(mx, __shfl_xor(mx, 32));
      const float mn = fmaxf(m_run[ni], mx);
      const float rs = exp2f(m_run[ni] - mn);
      m_run[ni] = mn;
      float sum = 0.f;
      #pragma unroll
      for (int mi = 0; mi < 4; ++mi)
        #pragma unroll
        for (int r = 0; r < 4; ++r){
          float e = exp2f(S[mi][ni][r] - mn);
          S[mi][ni][r] = e; sum += e;
        }
      sum += __shfl_xor(sum, 16); sum += __shfl_xor(sum, 32);
      d_run[ni] = d_run[ni]*rs + sum;
      #pragma unroll
      for (int me = 0; me < 4; ++me) Yacc[me][ni] *= rs;
    }
    // PV: A = V (e x l), B = P from regs (k-order matches D layout)
    #pragma unroll
    for (int ks = 0; ks < 2; ++ks){
      s16x8 Pf[4];
      #pragma unroll
      for (int ni = 0; ni < 4; ++ni){
        f32x4 a = S[2*ks][ni], b2 = S[2*ks+1][ni];
        s16x8 pf;
        #pragma unroll
        for (int j = 0; j < 4; ++j){
          pf[j]   = (short)f2bf(a[j]);
          pf[4+j] = (short)f2bf(b2[j]);
        }
        Pf[ni] = pf;
      }
      #pragma unroll
      for (int me = 0; me < 4; ++me){
        s16x4 vlo = *(const s16x4*)(Vb + (size_t)(me*16 + l15)*52 + ks*32 + g4);
        s16x4 vhi = *(const s16x4*)(Vb + (size_t)(me*16 + l15)*52 + ks*32 + 16 + g4);
        s16x8 Vf;
        #pragma unroll
        for (int j = 0; j < 4; ++j){ Vf[j] = vlo[j]; Vf[4+j] = vhi[j]; }
        #pragma unroll
        for (int ni = 0; ni < 4; ++ni)
          Yacc[me][ni] = mfma16(Vf, Pf[ni], Yacc[me][ni]);
      }
    }
  }
  const int n_pad = slo + (6 - shi);
  f32x4 bvf[4];
  #pragma unroll
  for (int me = 0; me < 4; ++me)
    bvf[me] = *(const f32x4*)(bv + n*64 + me*16 + g4);
  unsigned short* Yb = Yg + bnt*3136;
  #pragma unroll
  for (int ni = 0; ni < 4; ++ni){
    float rs = 1.f, pw = 0.f, d = d_run[ni];
    if (n_pad > 0){
      const float mf = fmaxf(m_run[ni], pad_l[ni]);
      rs = exp2f(m_run[ni] - mf);
      pw = (float)(n_pad*49) * exp2f(pad_l[ni] - mf);
      d = d_run[ni]*rs + pw;
    }
    const float inv = 1.f/d;
    const int p = ni*16 + l15;
    if (p < 49){
      #pragma unroll
      for (int me = 0; me < 4; ++me){
        s16x4 u;
        #pragma unroll
        for (int r = 0; r < 4; ++r)
          u[r] = (short)f2bf((Yacc[me][ni][r]*rs + pw*bvf[me][r])*inv);
        *(s16x4*)(Yb + (size_t)p*64 + me*16 + g4) = u;
      }
    }
  }
}

// ---------------- output projection + head-mean + residual (MFMA) ----------------
__global__ __launch_bounds__(512,2) void out_kernel(const unsigned short* __restrict__ Wo2,
    const unsigned short* __restrict__ Yg,
    const float* __restrict__ scale, const float* __restrict__ shift,
    const float* __restrict__ bo_sum, const float* __restrict__ x,
    float* __restrict__ out){
  __shared__ float S3[1536];
  const int bt = blockIdx.x, b = bt >> 5, t = bt & 31, tid = threadIdx.x;
  for (int i = tid; i < 1536; i += 512)
    S3[i] = (i < 512) ? scale[i] : (i < 1024 ? shift[i-512] : bo_sum[i-1024]);
  __syncthreads();
  const int wave = __builtin_amdgcn_readfirstlane(tid >> 6);
  const int lane = tid & 63, g = lane >> 4, l15 = lane & 15, g4 = (lane >> 4)*4;
  f32x4 acc[4][4];
  #pragma unroll
  for (int mi = 0; mi < 4; ++mi)
    #pragma unroll
    for (int ni = 0; ni < 4; ++ni) acc[mi][ni] = 0.f;
  #pragma unroll 2
  for (int ks = 0; ks < 16; ++ks){
    const int nh = ks >> 1;
    const unsigned short* Yb = Yg + ((size_t)(b*8 + nh)*32 + t)*3136 + (ks & 1)*32 + g*8;
    s16x8 Bf[4];
    #pragma unroll
    for (int ni = 0; ni < 4; ++ni)
      Bf[ni] = *(const s16x8*)(Yb + (ni*16 + l15)*64);
    #pragma unroll
    for (int mi = 0; mi < 4; ++mi){
      s16x8 Af = *(const s16x8*)(Wo2 + (size_t)(wave*64 + mi*16 + l15)*512 + ks*32 + g*8);
      #pragma unroll
      for (int ni = 0; ni < 4; ++ni)
        acc[mi][ni] = mfma16(Af, Bf[ni], acc[mi][ni]);
    }
  }
  #pragma unroll
  for (int mi = 0; mi < 4; ++mi){
    const int c0 = wave*64 + mi*16 + g4;
    const f32x4 sc = *(const f32x4*)&S3[c0];
    const f32x4 sh = *(const f32x4*)&S3[512 + c0];
    const f32x4 bs = *(const f32x4*)&S3[1024 + c0];
    #pragma unroll
    for (int ni = 0; ni < 4; ++ni){
      const int p = ni*16 + l15;
      if (p < 49){
        #pragma unroll
        for (int r = 0; r < 4; ++r){
          const int c = c0 + r;
          const size_t xi = ((size_t)(b*512 + c))*1568 + t*49 + p;
          out[xi] = acc[mi][ni][r] + bs[r] + x[xi]*sc[r] + sh[r];
        }
      }
    }
  }
}

extern "C" void kernel_launch(void* const* d_in, const int* in_sizes, int n_in_,
                              void* d_out, int out_size, void* d_ws, size_t ws_size,
                              hipStream_t stream){
  const float* x     = (const float*)d_in[0];
  const float* gamma = (const float*)d_in[1];
  const float* beta  = (const float*)d_in[2];
  const float* Wq    = (const float*)d_in[3];
  const float* bq    = (const float*)d_in[4];
  const float* Wk    = (const float*)d_in[5];
  const float* bk    = (const float*)d_in[6];
  const float* Wv    = (const float*)d_in[7];
  const float* bv    = (const float*)d_in[8];
  const float* Wo    = (const float*)d_in[9];
  const float* bo    = (const float*)d_in[10];
  float* out = (float*)d_out;

  char* ws = (char*)d_ws;
  float* scale  = (float*)ws;            // 512
  float* shift  = scale + 512;           // 512
  float* bo_sum = shift + 512;           // 512
  unsigned short* Wall = (unsigned short*)(ws + 8192);
  const size_t PAD = 16384;
  unsigned short* Wo2 = Wall + 786432;
  unsigned short* Xt  = Wo2 + 262144;
  unsigned short* Qg  = Xt + 8388608;
  unsigned short* Kg  = Qg + 6422528 + PAD;
  unsigned short* Vg  = Kg + 6422528 + PAD;
  unsigned short* Yg  = Vg + 6815744 + PAD;

  hipLaunchKernelGGL(stats_kernel, dim3(512), dim3(256), 0, stream,
                     x, gamma, beta, scale, shift);
  hipLaunchKernelGGL(pack_kernel, dim3(2049), dim3(512), 0, stream,
                     Wq, Wk, Wv, Wo, bo, Wall, Wo2, bo_sum);
  hipLaunchKernelGGL(xt_kernel, dim3(256), dim3(256), 0, stream,
                     x, scale, shift, Xt);
  hipLaunchKernelGGL(qkv_kernel, dim3(256), dim3(512), 0, stream,
                     Wall, Xt, bq, bk, bv, Qg, Kg, Vg);
  hipLaunchKernelGGL(attn_kernel, dim3(256), dim3(512), 0, stream,
                     Qg, Kg, Vg, bk, bv, Yg);
  hipLaunchKernelGGL(out_kernel, dim3(256), dim3(512), 0, stream,
                     Wo2, Yg, scale, shift, bo_sum, x, out);
}

// Round 3
// 128.437 us; speedup vs baseline: 16.3484x; 1.5827x over previous
//
#include <hip/hip_runtime.h>
#include <hip/hip_bf16.h>

// Shapes: B=8 C=512 T=32 H=W=7 P=49 N=8 E=64 K_WIN=7
// x: (B,C,T,H,W) fp32; out same fp32.

typedef float f32x4 __attribute__((ext_vector_type(4)));
typedef short s16x8 __attribute__((ext_vector_type(8)));
typedef short s16x4 __attribute__((ext_vector_type(4)));
typedef __bf16 bf16x8 __attribute__((ext_vector_type(8)));

static __device__ __forceinline__ float bf2f(unsigned short u){
  union { unsigned int i; float f; } x; x.i = ((unsigned int)u) << 16; return x.f;
}
static __device__ __forceinline__ unsigned short f2bf(float f){
  union { __hip_bfloat16 h; unsigned short u; } x; x.h = __float2bfloat16(f); return x.u;
}
static __device__ __forceinline__ f32x4 mfma16(s16x8 a, s16x8 b, f32x4 c){
  return __builtin_amdgcn_mfma_f32_16x16x32_bf16(
      __builtin_bit_cast(bf16x8, a), __builtin_bit_cast(bf16x8, b), c, 0, 0, 0);
}
static __device__ __forceinline__ void gload16(const unsigned short* g, unsigned short* l){
  __builtin_amdgcn_global_load_lds(
      (const __attribute__((address_space(1))) unsigned int*)g,
      (__attribute__((address_space(3))) unsigned int*)l, 16, 0, 0);
}

// ---------------- per-channel stats -> scale/shift ----------------
__global__ __launch_bounds__(256) void stats_kernel(const float* __restrict__ x,
    const float* __restrict__ gamma, const float* __restrict__ beta,
    float* __restrict__ scale, float* __restrict__ shift){
  const int c = blockIdx.x, tid = threadIdx.x;
  float s1 = 0.f, s2 = 0.f;
  const float* xc = x + (size_t)c*1568;
  for (int i = tid; i < 3136; i += 256){
    int b = i / 392, j = i - b*392;
    f32x4 v = *(const f32x4*)(xc + (size_t)b*802816 + j*4);
    s1 += v[0]+v[1]+v[2]+v[3];
    s2 += v[0]*v[0]+v[1]*v[1]+v[2]*v[2]+v[3]*v[3];
  }
  #pragma unroll
  for (int off = 32; off > 0; off >>= 1){
    s1 += __shfl_down(s1, off);
    s2 += __shfl_down(s2, off);
  }
  __shared__ float r1[4], r2[4];
  int wave = tid >> 6, lane = tid & 63;
  if (lane == 0){ r1[wave] = s1; r2[wave] = s2; }
  __syncthreads();
  if (tid == 0){
    float t1 = r1[0]+r1[1]+r1[2]+r1[3];
    float t2 = r2[0]+r2[1]+r2[2]+r2[3];
    const float inv = 1.f/12544.f;
    float mean = t1*inv;
    float var  = t2*inv - mean*mean;
    float sc = gamma[c]*rsqrtf(var + 1e-5f);
    scale[c] = sc;
    shift[c] = beta[c] - mean*sc;
  }
}

// ---------------- pack weights to bf16 ----------------
__global__ __launch_bounds__(512) void pack_kernel(const float* __restrict__ Wq,
    const float* __restrict__ Wk, const float* __restrict__ Wv,
    const float* __restrict__ Wo, const float* __restrict__ bo,
    unsigned short* __restrict__ Wall, unsigned short* __restrict__ Wo2,
    float* __restrict__ bo_sum){
  int i = blockIdx.x*512 + threadIdx.x;
  if (i < 786432){
    const float* W = (i < 262144) ? Wq : (i < 524288 ? Wk : Wv);
    Wall[i] = f2bf(W[i & 262143]);
  } else if (i < 1048576){
    int j = i - 786432;
    int c = j >> 9, k = j & 511, nn = k >> 6, e = k & 63;
    Wo2[j] = f2bf(Wo[((size_t)nn*512 + c)*64 + e] * 0.125f);
  } else if (i < 1049088){
    int c = i - 1048576;
    float s = 0.f;
    #pragma unroll
    for (int nn = 0; nn < 8; ++nn) s += bo[nn*512 + c];
    bo_sum[c] = s * 0.125f;
  }
}

// ---------------- normalize + transpose x -> Xt[bt][p(64)][c(512)] bf16 ----------------
__global__ __launch_bounds__(256) void xt_kernel(const float* __restrict__ x,
    const float* __restrict__ scale, const float* __restrict__ shift,
    unsigned short* __restrict__ Xt){
  __shared__ unsigned short Xc[512][52];
  const int bt = blockIdx.x, b = bt >> 5, t = bt & 31, tid = threadIdx.x;
  const float* xb = x + (size_t)b*802816 + t*49;
  for (int i = tid; i < 512*49; i += 256){
    int c = i / 49, p = i - c*49;
    Xc[c][p] = f2bf(xb[(size_t)c*1568 + p]*scale[c] + shift[c]);
  }
  __syncthreads();
  unsigned short* dst = Xt + (size_t)bt*32768;
  for (int i = tid; i < 4096; i += 256){
    int p = i & 63, c0 = (i >> 6) << 3;
    s16x8 v;
    #pragma unroll
    for (int j = 0; j < 8; ++j) v[j] = (p < 49) ? (short)Xc[c0+j][p] : (short)0;
    *(s16x8*)(dst + p*512 + c0) = v;
  }
}

// ---------------- QKV as tiled MFMA GEMM ----------------
// Wall(1536x512) x Xt^T(512x16384). 128x128 tiles, BK=32, dbuf LDS via
// global_load_lds (linear dest, pre-swizzled source; swizzled ds_read).
__global__ __launch_bounds__(256) void qkv_gemm(const unsigned short* __restrict__ Wall,
    const unsigned short* __restrict__ Xt,
    const float* __restrict__ bq, const float* __restrict__ bk, const float* __restrict__ bv,
    unsigned short* __restrict__ Qg, unsigned short* __restrict__ Kg,
    unsigned short* __restrict__ Vg){
  __shared__ unsigned short As[2][4096];
  __shared__ unsigned short Bs[2][4096];
  const int bid = blockIdx.x;
  const int id = (bid & 7)*192 + (bid >> 3);   // XCD-chunked (1536%8==0)
  const int bm = id % 12, bn = id / 12;        // bn-major within XCD: A L2-resident
  const int m0 = bm*128, n0 = bn*128;
  const int tid = threadIdx.x;
  const int w = __builtin_amdgcn_readfirstlane(tid >> 6);
  const int lane = tid & 63, l15 = lane & 15, g = lane >> 4, g4 = (lane >> 4)*4;
  const int wm = w >> 1, wn = w & 1;
  const int cA = w*128 + lane;
  int offA[4], offB[4];
  #pragma unroll
  for (int mi = 0; mi < 4; ++mi){
    int row = wm*64 + mi*16 + l15;
    offA[mi] = row*32 + ((g ^ ((row>>1)&3))<<3);
  }
  #pragma unroll
  for (int ni = 0; ni < 4; ++ni){
    int col = wn*64 + ni*16 + l15;
    offB[ni] = col*32 + ((g ^ ((col>>1)&3))<<3);
  }
  f32x4 acc[4][4];
  #pragma unroll
  for (int mi = 0; mi < 4; ++mi)
    #pragma unroll
    for (int ni = 0; ni < 4; ++ni) acc[mi][ni] = 0.f;

  auto stage = [&](int bufi, int ks){
    #pragma unroll
    for (int it = 0; it < 2; ++it){
      int c = cA + it*64;
      int row = c >> 2, slot = c & 3;
      int ko = ks*32 + ((slot ^ ((row>>1)&3))<<3);
      gload16(Wall + (size_t)(m0 + row)*512 + ko, &As[bufi][(w*128 + it*64)*8]);
      gload16(Xt   + (size_t)(n0 + row)*512 + ko, &Bs[bufi][(w*128 + it*64)*8]);
    }
  };
  auto compute = [&](int bufi){
    s16x8 Af[4], Bf[4];
    #pragma unroll
    for (int mi = 0; mi < 4; ++mi) Af[mi] = *(const s16x8*)&As[bufi][offA[mi]];
    #pragma unroll
    for (int ni = 0; ni < 4; ++ni) Bf[ni] = *(const s16x8*)&Bs[bufi][offB[ni]];
    #pragma unroll
    for (int mi = 0; mi < 4; ++mi)
      #pragma unroll
      for (int ni = 0; ni < 4; ++ni)
        acc[mi][ni] = mfma16(Af[mi], Bf[ni], acc[mi][ni]);
  };

  stage(0, 0);
  __syncthreads();
  #pragma unroll 1
  for (int kk = 0; kk < 8; ++kk){
    stage(1, kk*2 + 1);
    compute(0);
    __syncthreads();
    if (kk < 7) stage(0, kk*2 + 2);
    compute(1);
    __syncthreads();
  }

  // epilogue: wave quadrant = one (which, head, bt)
  const int qb = bm*2 + wm;            // 0..23
  const int which = qb >> 3, n = qb & 7;
  const int bt = bn*2 + wn, b = bt >> 5, t = bt & 31;
  const size_t bnt = ((size_t)(b*8 + n)*32 + t);
  const float* bias = which == 0 ? bq : (which == 1 ? bk : bv);
  #pragma unroll
  for (int mi = 0; mi < 4; ++mi){
    const int e0 = mi*16 + g4;
    const f32x4 bb = *(const f32x4*)(bias + n*64 + e0);
    #pragma unroll
    for (int ni = 0; ni < 4; ++ni){
      const int p = ni*16 + l15;
      f32x4 v = acc[mi][ni] + bb;
      if (which == 0) v *= 1.4426950408889634f;
      if (p < 49){
        if (which < 2){
          s16x4 u;
          #pragma unroll
          for (int r = 0; r < 4; ++r) u[r] = (short)f2bf(v[r]);
          *(s16x4*)((which == 0 ? Qg : Kg) + (bnt*49 + p)*64 + e0) = u;
        } else {
          #pragma unroll
          for (int r = 0; r < 4; ++r)
            Vg[bnt*3328 + (size_t)(e0 + r)*52 + p] = f2bf(v[r]);
        }
      }
    }
  }
}

// ---------------- local attention (MFMA, online softmax in registers) ----------------
__global__ __launch_bounds__(512,2) void attn_kernel(const unsigned short* __restrict__ Qg,
    const unsigned short* __restrict__ Kg, const unsigned short* __restrict__ Vg,
    const float* __restrict__ bk, const float* __restrict__ bv,
    unsigned short* __restrict__ Yg){
  const int bid = blockIdx.x;
  const int bt = ((bid & 7) << 5) | (bid >> 3);
  const int b = bt >> 5, t = bt & 31, tid = threadIdx.x;
  const int n = __builtin_amdgcn_readfirstlane(tid >> 6);
  const int lane = tid & 63, g = lane >> 4, l15 = lane & 15, g4 = (lane >> 4)*4;
  const size_t bnt = ((size_t)(b*8 + n)*32 + t);
  const unsigned short* Qb = Qg + bnt*3136;
  s16x8 Qf[4][2];
  #pragma unroll
  for (int ni = 0; ni < 4; ++ni)
    #pragma unroll
    for (int ks = 0; ks < 2; ++ks)
      Qf[ni][ks] = *(const s16x8*)(Qb + (ni*16 + l15)*64 + ks*32 + g*8);
  const float* bkp = bk + n*64;
  f32x4 bkf[2][2];
  bkf[0][0] = *(const f32x4*)(bkp + g*8);      bkf[0][1] = *(const f32x4*)(bkp + g*8 + 4);
  bkf[1][0] = *(const f32x4*)(bkp + 32 + g*8); bkf[1][1] = *(const f32x4*)(bkp + 32 + g*8 + 4);
  float pad_l[4];
  #pragma unroll
  for (int ni = 0; ni < 4; ++ni){
    float s = 0.f;
    #pragma unroll
    for (int ks = 0; ks < 2; ++ks)
      #pragma unroll
      for (int h = 0; h < 2; ++h)
        #pragma unroll
        for (int j = 0; j < 4; ++j)
          s += bf2f((unsigned short)Qf[ni][ks][h*4+j]) * bkf[ks][h][j];
    s += __shfl_xor(s, 16); s += __shfl_xor(s, 32);
    pad_l[ni] = s;
  }
  float m_run[4], d_run[4];
  f32x4 Yacc[4][4];
  #pragma unroll
  for (int ni = 0; ni < 4; ++ni){
    m_run[ni] = -1e30f; d_run[ni] = 0.f;
    #pragma unroll
    for (int me = 0; me < 4; ++me) Yacc[me][ni] = 0.f;
  }
  int slo = 3 - t; if (slo < 0) slo = 0;
  int shi = 34 - t; if (shi > 6) shi = 6;
  for (int s = slo; s <= shi; ++s){
    const int tt = t + s - 3;
    const unsigned short* Kb = Kg + ((size_t)(b*8 + n)*32 + tt)*3136;
    const unsigned short* Vb = Vg + ((size_t)(b*8 + n)*32 + tt)*3328;
    f32x4 S[4][4];
    #pragma unroll
    for (int mi = 0; mi < 4; ++mi)
      #pragma unroll
      for (int ni = 0; ni < 4; ++ni) S[mi][ni] = 0.f;
    __builtin_amdgcn_s_setprio(1);
    #pragma unroll
    for (int ks = 0; ks < 2; ++ks)
      #pragma unroll
      for (int mi = 0; mi < 4; ++mi){
        s16x8 Kf = *(const s16x8*)(Kb + (mi*16 + l15)*64 + ks*32 + g*8);
        #pragma unroll
        for (int ni = 0; ni < 4; ++ni)
          S[mi][ni] = mfma16(Kf, Qf[ni][ks], S[mi][ni]);
      }
    __builtin_amdgcn_s_setprio(0);
    #pragma unroll
    for (int r = 0; r < 4; ++r){
      const bool bad = (g4 + r) >= 1;
      #pragma unroll
      for (int ni = 0; ni < 4; ++ni)
        S[3][ni][r] = bad ? -1e30f : S[3][ni][r];
    }
    #pragma unroll
    for (int ni = 0; ni < 4; ++ni){
      float mx = -1e30f;
      #pragma unroll
      for (int mi = 0; mi < 4; ++mi)
        #pragma unroll
        for (int r = 0; r < 4; ++r) mx = fmaxf(mx, S[mi][ni][r]);
      mx = fmaxf(mx, __shfl_xor(mx, 16));
      mx = fmaxf(mx, __shfl_xor(mx, 32));
      const float mn = fmaxf(m_run[ni], mx);
      const float rs = exp2f(m_run[ni] - mn);
      m_run[ni] = mn;
      float sum = 0.f;
      #pragma unroll
      for (int mi = 0; mi < 4; ++mi)
        #pragma unroll
        for (int r = 0; r < 4; ++r){
          float e = exp2f(S[mi][ni][r] - mn);
          S[mi][ni][r] = e; sum += e;
        }
      sum += __shfl_xor(sum, 16); sum += __shfl_xor(sum, 32);
      d_run[ni] = d_run[ni]*rs + sum;
      #pragma unroll
      for (int me = 0; me < 4; ++me) Yacc[me][ni] *= rs;
    }
    #pragma unroll
    for (int ks = 0; ks < 2; ++ks){
      s16x8 Pf[4];
      #pragma unroll
      for (int ni = 0; ni < 4; ++ni){
        f32x4 a = S[2*ks][ni], b2 = S[2*ks+1][ni];
        s16x8 pf;
        #pragma unroll
        for (int j = 0; j < 4; ++j){
          pf[j]   = (short)f2bf(a[j]);
          pf[4+j] = (short)f2bf(b2[j]);
        }
        Pf[ni] = pf;
      }
      __builtin_amdgcn_s_setprio(1);
      #pragma unroll
      for (int me = 0; me < 4; ++me){
        s16x4 vlo = *(const s16x4*)(Vb + (size_t)(me*16 + l15)*52 + ks*32 + g4);
        s16x4 vhi = *(const s16x4*)(Vb + (size_t)(me*16 + l15)*52 + ks*32 + 16 + g4);
        s16x8 Vf;
        #pragma unroll
        for (int j = 0; j < 4; ++j){ Vf[j] = vlo[j]; Vf[4+j] = vhi[j]; }
        #pragma unroll
        for (int ni = 0; ni < 4; ++ni)
          Yacc[me][ni] = mfma16(Vf, Pf[ni], Yacc[me][ni]);
      }
      __builtin_amdgcn_s_setprio(0);
    }
  }
  const int n_pad = slo + (6 - shi);
  f32x4 bvf[4];
  #pragma unroll
  for (int me = 0; me < 4; ++me)
    bvf[me] = *(const f32x4*)(bv + n*64 + me*16 + g4);
  unsigned short* Yb = Yg + bnt*3136;
  #pragma unroll
  for (int ni = 0; ni < 4; ++ni){
    float rs = 1.f, pw = 0.f, d = d_run[ni];
    if (n_pad > 0){
      const float mf = fmaxf(m_run[ni], pad_l[ni]);
      rs = exp2f(m_run[ni] - mf);
      pw = (float)(n_pad*49) * exp2f(pad_l[ni] - mf);
      d = d_run[ni]*rs + pw;
    }
    const float inv = 1.f/d;
    const int p = ni*16 + l15;
    if (p < 49){
      #pragma unroll
      for (int me = 0; me < 4; ++me){
        s16x4 u;
        #pragma unroll
        for (int r = 0; r < 4; ++r)
          u[r] = (short)f2bf((Yacc[me][ni][r]*rs + pw*bvf[me][r])*inv);
        *(s16x4*)(Yb + (size_t)p*64 + me*16 + g4) = u;
      }
    }
  }
}

// ---------------- output projection as tiled MFMA GEMM ----------------
// Wo2(512x512) x Yg(512x16384), residual from Xt (bf16), +bo_sum, scatter to out.
__global__ __launch_bounds__(256) void out_gemm(const unsigned short* __restrict__ Wo2,
    const unsigned short* __restrict__ Yg, const unsigned short* __restrict__ Xt,
    const float* __restrict__ scale, const float* __restrict__ shift,
    const float* __restrict__ bo_sum, float* __restrict__ out){
  __shared__ unsigned short As[2][4096];
  __shared__ unsigned short Bs[2][4096];
  const int bid = blockIdx.x;
  const int id = (bid & 7)*64 + (bid >> 3);    // 512%8==0
  const int bm = id % 4, bn = id / 4;
  const int m0 = bm*128, n0 = bn*128;
  const int tid = threadIdx.x;
  const int w = __builtin_amdgcn_readfirstlane(tid >> 6);
  const int lane = tid & 63, l15 = lane & 15, g = lane >> 4, g4 = (lane >> 4)*4;
  const int wm = w >> 1, wn = w & 1;
  const int cA = w*128 + lane;
  int offA[4], offB[4];
  #pragma unroll
  for (int mi = 0; mi < 4; ++mi){
    int row = wm*64 + mi*16 + l15;
    offA[mi] = row*32 + ((g ^ ((row>>1)&3))<<3);
  }
  #pragma unroll
  for (int ni = 0; ni < 4; ++ni){
    int col = wn*64 + ni*16 + l15;
    offB[ni] = col*32 + ((g ^ ((col>>1)&3))<<3);
  }
  f32x4 acc[4][4];
  #pragma unroll
  for (int mi = 0; mi < 4; ++mi)
    #pragma unroll
    for (int ni = 0; ni < 4; ++ni) acc[mi][ni] = 0.f;

  auto stage = [&](int bufi, int ks){
    const int nh = ks >> 1, eo = (ks & 1)*32;
    #pragma unroll
    for (int it = 0; it < 2; ++it){
      int c = cA + it*64;
      int row = c >> 2, slot = c & 3;
      int sw = ((slot ^ ((row>>1)&3))<<3);
      gload16(Wo2 + (size_t)(m0 + row)*512 + ks*32 + sw, &As[bufi][(w*128 + it*64)*8]);
      const int col = n0 + row, btc = col >> 6, p = col & 63;
      const size_t bb = ((size_t)((btc >> 5)*8 + nh)*32 + (btc & 31));
      gload16(Yg + bb*3136 + p*64 + eo + sw, &Bs[bufi][(w*128 + it*64)*8]);
    }
  };
  auto compute = [&](int bufi){
    s16x8 Af[4], Bf[4];
    #pragma unroll
    for (int mi = 0; mi < 4; ++mi) Af[mi] = *(const s16x8*)&As[bufi][offA[mi]];
    #pragma unroll
    for (int ni = 0; ni < 4; ++ni) Bf[ni] = *(const s16x8*)&Bs[bufi][offB[ni]];
    #pragma unroll
    for (int mi = 0; mi < 4; ++mi)
      #pragma unroll
      for (int ni = 0; ni < 4; ++ni)
        acc[mi][ni] = mfma16(Af[mi], Bf[ni], acc[mi][ni]);
  };

  stage(0, 0);
  __syncthreads();
  #pragma unroll 1
  for (int kk = 0; kk < 8; ++kk){
    stage(1, kk*2 + 1);
    compute(0);
    __syncthreads();
    if (kk < 7) stage(0, kk*2 + 2);
    compute(1);
    __syncthreads();
  }

  const int cb = m0 + wm*64;
  const int bt = bn*2 + wn, b = bt >> 5, t = bt & 31;
  const unsigned short* XtB = Xt + (size_t)bt*32768;
  #pragma unroll
  for (int mi = 0; mi < 4; ++mi){
    const int c0 = cb + mi*16 + g4;
    const f32x4 sc = *(const f32x4*)(bo_sum + c0);
    #pragma unroll
    for (int ni = 0; ni < 4; ++ni){
      const int p = ni*16 + l15;
      if (p < 49){
        s16x4 xb = *(const s16x4*)(XtB + p*512 + c0);
        #pragma unroll
        for (int r = 0; r < 4; ++r){
          const int c = c0 + r;
          out[((size_t)(b*512 + c))*1568 + t*49 + p] =
              acc[mi][ni][r] + sc[r] + bf2f((unsigned short)xb[r]);
        }
      }
    }
  }
}

extern "C" void kernel_launch(void* const* d_in, const int* in_sizes, int n_in_,
                              void* d_out, int out_size, void* d_ws, size_t ws_size,
                              hipStream_t stream){
  const float* x     = (const float*)d_in[0];
  const float* gamma = (const float*)d_in[1];
  const float* beta  = (const float*)d_in[2];
  const float* Wq    = (const float*)d_in[3];
  const float* bq    = (const float*)d_in[4];
  const float* Wk    = (const float*)d_in[5];
  const float* bk    = (const float*)d_in[6];
  const float* Wv    = (const float*)d_in[7];
  const float* bv    = (const float*)d_in[8];
  const float* Wo    = (const float*)d_in[9];
  const float* bo    = (const float*)d_in[10];
  float* out = (float*)d_out;

  char* ws = (char*)d_ws;
  float* scale  = (float*)ws;            // 512
  float* shift  = scale + 512;           // 512
  float* bo_sum = shift + 512;           // 512
  unsigned short* Wall = (unsigned short*)(ws + 8192);
  const size_t PAD = 16384;
  unsigned short* Wo2 = Wall + 786432;
  unsigned short* Xt  = Wo2 + 262144;
  unsigned short* Qg  = Xt + 8388608;
  unsigned short* Kg  = Qg + 6422528 + PAD;
  unsigned short* Vg  = Kg + 6422528 + PAD;
  unsigned short* Yg  = Vg + 6815744 + PAD;   // Yg + 6422528 + PAD tail slack

  hipLaunchKernelGGL(stats_kernel, dim3(512), dim3(256), 0, stream,
                     x, gamma, beta, scale, shift);
  hipLaunchKernelGGL(pack_kernel, dim3(2049), dim3(512), 0, stream,
                     Wq, Wk, Wv, Wo, bo, Wall, Wo2, bo_sum);
  hipLaunchKernelGGL(xt_kernel, dim3(256), dim3(256), 0, stream,
                     x, scale, shift, Xt);
  hipLaunchKernelGGL(qkv_gemm, dim3(1536), dim3(256), 0, stream,
                     Wall, Xt, bq, bk, bv, Qg, Kg, Vg);
  hipLaunchKernelGGL(attn_kernel, dim3(256), dim3(512), 0, stream,
                     Qg, Kg, Vg, bk, bv, Yg);
  hipLaunchKernelGGL(out_gemm, dim3(512), dim3(256), 0, stream,
                     Wo2, Yg, Xt, scale, shift, bo_sum, out);
}